// Round 1
// baseline (1233.711 us; speedup 1.0000x reference)
//
#include <hip/hip_runtime.h>
#include <cstdint>
#include <cstddef>

#define DI __device__ __forceinline__

constexpr int N = 50000;
constexpr int E = 800000;
constexpr int NG = 8;

// ---------- ws layout ----------
constexpr size_t AL(size_t x){ return (x + 1023) & ~size_t(1023); }
constexpr size_t OFF_SCAL   = 0;                          // 4 doubles (norm sums)
constexpr size_t OFF_GSUM   = 1024;                       // 512 floats
constexpr size_t OFF_GCNT   = OFF_GSUM + 2048;            // 8 floats
constexpr size_t OFF_DEG    = 4096;                       // N ints
constexpr size_t ZERO_BYTES = OFF_DEG + size_t(N)*4;      // zeroed each launch
constexpr size_t OFF_ROWPTR = AL(ZERO_BYTES);             // (N+1) ints
constexpr size_t OFF_CURSOR = AL(OFF_ROWPTR + size_t(N+1)*4);
constexpr size_t OFF_BSUM   = AL(OFF_CURSOR + size_t(N)*4);
constexpr size_t OFF_BOFF   = AL(OFF_BSUM + 1024);
constexpr size_t OFF_COL    = AL(OFF_BOFF + 1024);        // E int2
constexpr size_t OFF_ALPHA  = AL(OFF_COL + size_t(E)*8);  // E*2 floats
constexpr size_t OFF_A      = AL(OFF_ALPHA + size_t(E)*2*4); // N*128 f
constexpr size_t OFF_B      = AL(OFF_A + size_t(N)*128*4);   // N*256 f
constexpr size_t OFF_C      = AL(OFF_B + size_t(N)*256*4);   // N*128 f (also hosts h0 [N,64])

template<int START>
DI float wred(float v){
  #pragma unroll
  for (int o = START; o > 0; o >>= 1) v += __shfl_xor(v, o);
  return v;
}

DI float elu(float v){ return v > 0.f ? v : (__expf(v) - 1.f); }

// ---------- CSR build ----------
__global__ void k_deg(const int* __restrict__ ei, int* __restrict__ deg){
  for (int e = blockIdx.x*blockDim.x + threadIdx.x; e < E; e += gridDim.x*blockDim.x)
    atomicAdd(&deg[ei[E + e]], 1);
}

__global__ __launch_bounds__(256) void k_scan1(const int* __restrict__ deg,
                                               int* __restrict__ rowptr,
                                               int* __restrict__ bsum){
  __shared__ int s[256];
  int t = threadIdx.x, i = blockIdx.x*256 + t;
  int v = (i < N) ? deg[i] : 0;
  s[t] = v; __syncthreads();
  for (int off = 1; off < 256; off <<= 1){
    int x = (t >= off) ? s[t-off] : 0;
    __syncthreads();
    s[t] += x; __syncthreads();
  }
  if (i < N) rowptr[i] = s[t] - v;
  if (t == 255) bsum[blockIdx.x] = s[255];
}

__global__ __launch_bounds__(256) void k_scan2(const int* __restrict__ bsum,
                                               int* __restrict__ boff, int nb){
  __shared__ int s[256];
  int t = threadIdx.x;
  int v = (t < nb) ? bsum[t] : 0;
  s[t] = v; __syncthreads();
  for (int off = 1; off < 256; off <<= 1){
    int x = (t >= off) ? s[t-off] : 0;
    __syncthreads();
    s[t] += x; __syncthreads();
  }
  if (t < nb) boff[t] = s[t] - v;
}

__global__ __launch_bounds__(256) void k_scan3(int* __restrict__ rowptr,
                                               const int* __restrict__ boff,
                                               int* __restrict__ cursor){
  int t = threadIdx.x, i = blockIdx.x*256 + t;
  if (i < N){
    int v = rowptr[i] + boff[blockIdx.x];
    rowptr[i] = v;
    cursor[i] = v;
  }
  if (i == 0) rowptr[N] = E;
}

__global__ void k_fill(const int* __restrict__ ei, int* __restrict__ cursor,
                       int2* __restrict__ col){
  for (int e = blockIdx.x*blockDim.x + threadIdx.x; e < E; e += gridDim.x*blockDim.x){
    int d = ei[E + e];
    int pos = atomicAdd(&cursor[d], 1);
    col[pos] = make_int2(ei[e], e);
  }
}

// ---------- node transform: h0 = LN(elu(x @ nt_w + nt_b)) ----------
__global__ __launch_bounds__(256) void k_node_transform(
    const float* __restrict__ x, const float* __restrict__ w,
    const float* __restrict__ b, const float* __restrict__ lnw,
    const float* __restrict__ lnb, float* __restrict__ h0){
  int wid = (blockIdx.x*256 + threadIdx.x) >> 6;
  int l = threadIdx.x & 63;
  if (wid >= N) return;
  float xv = x[wid*32 + (l & 31)];
  float acc = b[l];
  #pragma unroll
  for (int k = 0; k < 32; ++k){
    float hk = __shfl(xv, k);
    acc = fmaf(hk, w[k*64 + l], acc);
  }
  float v = elu(acc);
  float mu = wred<32>(v) * (1.f/64.f);
  float xc = v - mu;
  float var = wred<32>(xc*xc) * (1.f/64.f);
  float rs = rsqrtf(var + 1e-5f);
  h0[wid*64 + l] = xc*rs*lnw[l] + lnb[l];
}

// ---------- linear: out[:, off:off+COLS] (stride out_stride) = h @ W + bias ----------
template<int K, int COLS>
__global__ __launch_bounds__(256) void k_lin(
    const float* __restrict__ h, const float* __restrict__ W,
    const float* __restrict__ bias, float* __restrict__ out,
    int out_stride, int out_off){
  constexpr int CB = 64;
  constexpr int NCB = COLS / CB;
  constexpr int NT = 32;
  constexpr int KQ = K / 4;
  __shared__ float Wl[K][CB];
  __shared__ float Hl[NT][K + 4];
  const int tid = threadIdx.x;
  const int cb = blockIdx.x % NCB;
  const int tile0 = blockIdx.x / NCB;
  const int tstep = gridDim.x / NCB;
  for (int idx = tid; idx < K*CB; idx += 256){
    int k = idx >> 6, c = idx & 63;
    Wl[k][c] = W[k*COLS + cb*CB + c];
  }
  const int nl = tid >> 4;
  const int cq = tid & 15;
  const float* bb = bias + cb*CB + cq*4;
  float4 b4 = make_float4(bb[0], bb[1], bb[2], bb[3]);
  constexpr int NTILES = (N + NT - 1)/NT;
  for (int tile = tile0; tile < NTILES; tile += tstep){
    int n0 = tile*NT;
    __syncthreads();
    for (int idx = tid; idx < NT*KQ; idx += 256){
      int nn = idx / KQ, kq = idx % KQ;
      float4 v = make_float4(0,0,0,0);
      int n = n0 + nn;
      if (n < N) v = ((const float4*)(h + size_t(n)*K))[kq];
      *(((float4*)&Hl[nn][0]) + kq) = v;
    }
    __syncthreads();
    float4 a0 = make_float4(0,0,0,0), a1 = a0;
    #pragma unroll 8
    for (int k = 0; k < K; ++k){
      float4 w4 = ((const float4*)&Wl[k][0])[cq];
      float h0v = Hl[nl][k];
      float h1v = Hl[nl+16][k];
      a0.x = fmaf(h0v, w4.x, a0.x); a0.y = fmaf(h0v, w4.y, a0.y);
      a0.z = fmaf(h0v, w4.z, a0.z); a0.w = fmaf(h0v, w4.w, a0.w);
      a1.x = fmaf(h1v, w4.x, a1.x); a1.y = fmaf(h1v, w4.y, a1.y);
      a1.z = fmaf(h1v, w4.z, a1.z); a1.w = fmaf(h1v, w4.w, a1.w);
    }
    int na = n0 + nl, nb2 = n0 + nl + 16;
    if (na < N){
      float4 o = make_float4(a0.x+b4.x, a0.y+b4.y, a0.z+b4.z, a0.w+b4.w);
      ((float4*)(out + size_t(na)*out_stride + out_off + cb*CB))[cq] = o;
    }
    if (nb2 < N){
      float4 o = make_float4(a1.x+b4.x, a1.y+b4.y, a1.z+b4.z, a1.w+b4.w);
      ((float4*)(out + size_t(nb2)*out_stride + out_off + cb*CB))[cq] = o;
    }
  }
}

// ---------- alpha: raw attention logits per edge ----------
template<int H>
__global__ __launch_bounds__(256) void k_alpha(
    const float* __restrict__ xlr, const float* __restrict__ we,
    const float* __restrict__ att, const int* __restrict__ ei,
    const float* __restrict__ ea, float* __restrict__ alpha){
  constexpr int HC = H*64;
  constexpr int STRIDE = 2*HC;
  __shared__ float weL[16*HC];
  __shared__ float attL[HC];
  const int tid = threadIdx.x;
  for (int idx = tid; idx < 16*HC; idx += 256) weL[idx] = we[idx];
  for (int idx = tid; idx < HC; idx += 256) attL[idx] = att[idx];
  __syncthreads();
  const int l = tid & 63;
  int wid = (blockIdx.x*256 + tid) >> 6;
  const int NW = (gridDim.x*256) >> 6;
  for (int e = wid; e < E; e += NW){
    int s = ei[e], d = ei[E + e];
    const float4* eap = (const float4*)(ea + size_t(e)*16);
    float4 e0 = eap[0], e1 = eap[1], e2 = eap[2], e3 = eap[3];
    float eav[16] = {e0.x,e0.y,e0.z,e0.w, e1.x,e1.y,e1.z,e1.w,
                     e2.x,e2.y,e2.z,e2.w, e3.x,e3.y,e3.z,e3.w};
    if constexpr (H == 2){
      float2 xl = ((const float2*)(xlr + size_t(s)*STRIDE))[l];
      float2 xr = ((const float2*)(xlr + size_t(d)*STRIDE + HC))[l];
      float2 ech = make_float2(0,0);
      const float2* we2 = (const float2*)weL;
      #pragma unroll
      for (int k = 0; k < 16; ++k){
        float2 wv = we2[k*64 + l];
        ech.x = fmaf(eav[k], wv.x, ech.x);
        ech.y = fmaf(eav[k], wv.y, ech.y);
      }
      float m0 = xl.x + xr.x + ech.x;
      float m1 = xl.y + xr.y + ech.y;
      m0 = m0 > 0.f ? m0 : 0.2f*m0;
      m1 = m1 > 0.f ? m1 : 0.2f*m1;
      float2 at = ((const float2*)attL)[l];
      float part = m0*at.x + m1*at.y;
      part = wred<16>(part);               // reduce within 32-lane half (per head)
      if ((l & 31) == 0) alpha[size_t(e)*2 + (l >> 5)] = part;
    } else {
      float xl = xlr[size_t(s)*STRIDE + l];
      float xr = xlr[size_t(d)*STRIDE + HC + l];
      float ech = 0.f;
      #pragma unroll
      for (int k = 0; k < 16; ++k) ech = fmaf(eav[k], weL[k*64 + l], ech);
      float m0 = xl + xr + ech;
      m0 = m0 > 0.f ? m0 : 0.2f*m0;
      float part = m0 * attL[l];
      part = wred<32>(part);
      if (l == 0) alpha[e] = part;
    }
  }
}

// ---------- aggregate: online softmax over CSR incoming edges ----------
template<int H>
__global__ __launch_bounds__(256) void k_agg(
    const float* __restrict__ xlr, const float* __restrict__ alpha,
    const int* __restrict__ rowptr, const int2* __restrict__ col,
    const float* __restrict__ bias, float* __restrict__ out){
  constexpr int HC = H*64;
  constexpr int STRIDE = 2*HC;
  const int tid = threadIdx.x;
  const int l = tid & 63;
  int n = (blockIdx.x*256 + tid) >> 6;
  if (n >= N) return;
  int beg = rowptr[n], end = rowptr[n+1];
  float m = -INFINITY, d = 0.f;
  float acc0 = 0.f, acc1 = 0.f;
  const int head = (H == 2) ? (l >> 5) : 0;
  for (int i = beg; i < end; ++i){
    int2 ent = col[i];
    float a = alpha[size_t(ent.y)*H + head];
    if (a > m){
      float sc = __expf(m - a);       // exp(-inf)=0 on first edge
      d *= sc; acc0 *= sc; acc1 *= sc; m = a;
    }
    float p = __expf(a - m);
    d += p;
    if constexpr (H == 2){
      float2 xv = ((const float2*)(xlr + size_t(ent.x)*STRIDE))[l];
      acc0 = fmaf(p, xv.x, acc0);
      acc1 = fmaf(p, xv.y, acc1);
    } else {
      float xv = xlr[size_t(ent.x)*STRIDE + l];
      acc0 = fmaf(p, xv, acc0);
    }
  }
  float inv = 1.f / (d + 1e-16f);
  if constexpr (H == 2){
    float2 o;
    o.x = acc0*inv + bias[2*l];
    o.y = acc1*inv + bias[2*l+1];
    ((float2*)(out + size_t(n)*HC))[l] = o;
  } else {
    out[size_t(n)*HC + l] = acc0*inv + bias[l];
  }
}

// ---------- graph norm (global scalar) ----------
__global__ __launch_bounds__(256) void k_gn_reduce(const float* __restrict__ xin,
                                                   double* __restrict__ scal){
  const size_t M4 = size_t(N)*128/4;
  float s = 0.f, s2 = 0.f;
  for (size_t i = size_t(blockIdx.x)*256 + threadIdx.x; i < M4; i += size_t(gridDim.x)*256){
    float4 v = ((const float4*)xin)[i];
    s  += v.x + v.y + v.z + v.w;
    s2 += v.x*v.x + v.y*v.y + v.z*v.z + v.w*v.w;
  }
  s = wred<32>(s); s2 = wred<32>(s2);
  __shared__ float bs[4], bs2[4];
  int w = threadIdx.x >> 6;
  if ((threadIdx.x & 63) == 0){ bs[w] = s; bs2[w] = s2; }
  __syncthreads();
  if (threadIdx.x == 0){
    double ts = 0, ts2 = 0;
    for (int i = 0; i < 4; ++i){ ts += (double)bs[i]; ts2 += (double)bs2[i]; }
    atomicAdd(&scal[0], ts);
    atomicAdd(&scal[1], ts2);
  }
}

__global__ __launch_bounds__(256) void k_gn_apply(
    const float* __restrict__ xin, const double* __restrict__ scal,
    const float* __restrict__ w, const float* __restrict__ b,
    float* __restrict__ out){
  const double invM = 1.0 / (double(N)*128.0);
  double mu_d = scal[0]*invM;
  double ex2  = scal[1]*invM;
  float mu = (float)mu_d;
  float var = (float)(ex2 - mu_d*mu_d);
  float rs = rsqrtf(var + 1e-5f);
  const size_t M4 = size_t(N)*128/4;
  for (size_t i = size_t(blockIdx.x)*256 + threadIdx.x; i < M4; i += size_t(gridDim.x)*256){
    float4 v = ((const float4*)xin)[i];
    int cq = int(i & 31);
    float4 wv = ((const float4*)w)[cq];
    float4 bv = ((const float4*)b)[cq];
    v.x = elu((v.x - mu)*rs*wv.x + bv.x);
    v.y = elu((v.y - mu)*rs*wv.y + bv.y);
    v.z = elu((v.z - mu)*rs*wv.z + bv.z);
    v.w = elu((v.w - mu)*rs*wv.w + bv.w);
    ((float4*)out)[i] = v;
  }
}

// ---------- heads + pooling ----------
__global__ __launch_bounds__(256) void k_pool(
    const float* __restrict__ h3, const int* __restrict__ batch,
    const float* __restrict__ pw, const float* __restrict__ pb,
    float* __restrict__ outv, float* __restrict__ gsum, float* __restrict__ gcnt){
  __shared__ float ls[512];
  __shared__ float lc[8];
  int tid = threadIdx.x;
  if (tid < 8) lc[tid] = 0.f;
  for (int i = tid; i < 512; i += 256) ls[i] = 0.f;
  __syncthreads();
  int l = tid & 63;
  int wid = (blockIdx.x*256 + tid) >> 6;
  int NW = (gridDim.x*256) >> 6;
  float pwl = pw[l];
  for (int n = wid; n < N; n += NW){
    float v = h3[size_t(n)*64 + l];
    float pp = wred<32>(v*pwl);
    if (l == 0) outv[n] = pp + pb[0];
    int g = batch[n];
    atomicAdd(&ls[g*64 + l], v);
    if (l == 0) atomicAdd(&lc[g], 1.f);
  }
  __syncthreads();
  for (int i = tid; i < 512; i += 256) atomicAdd(&gsum[i], ls[i]);
  if (tid < 8) atomicAdd(&gcnt[tid], lc[tid]);
}

__global__ __launch_bounds__(512) void k_head(
    const float* __restrict__ gsum, const float* __restrict__ gcnt,
    const float* __restrict__ hw, const float* __restrict__ hb,
    float* __restrict__ outv){
  int g = threadIdx.x >> 6, l = threadIdx.x & 63;
  float cnt = fmaxf(gcnt[g], 1.f);
  float emb = gsum[g*64 + l] / cnt;
  float p = wred<32>(emb*hw[l]);
  if (l == 0) outv[N + g] = p + hb[0];
}

extern "C" void kernel_launch(void* const* d_in, const int* in_sizes, int n_in,
                              void* d_out, int out_size, void* d_ws, size_t ws_size,
                              hipStream_t stream){
  const float* x      = (const float*)d_in[0];
  const int*   ei     = (const int*)  d_in[1];
  const float* ea     = (const float*)d_in[2];
  const int*   batch  = (const int*)  d_in[3];
  const float* nt_w   = (const float*)d_in[4];
  const float* nt_b   = (const float*)d_in[5];
  const float* ln0_w  = (const float*)d_in[6];
  const float* ln0_b  = (const float*)d_in[7];
  const float* c1_wl  = (const float*)d_in[8];
  const float* c1_bl  = (const float*)d_in[9];
  const float* c1_wr  = (const float*)d_in[10];
  const float* c1_br  = (const float*)d_in[11];
  const float* c1_we  = (const float*)d_in[12];
  const float* c1_att = (const float*)d_in[13];
  const float* c1_b   = (const float*)d_in[14];
  const float* n1_w   = (const float*)d_in[15];
  const float* n1_b   = (const float*)d_in[16];
  const float* c2_wl  = (const float*)d_in[17];
  const float* c2_bl  = (const float*)d_in[18];
  const float* c2_wr  = (const float*)d_in[19];
  const float* c2_br  = (const float*)d_in[20];
  const float* c2_we  = (const float*)d_in[21];
  const float* c2_att = (const float*)d_in[22];
  const float* c2_b   = (const float*)d_in[23];
  const float* n2_w   = (const float*)d_in[24];
  const float* n2_b   = (const float*)d_in[25];
  const float* c3_wl  = (const float*)d_in[26];
  const float* c3_bl  = (const float*)d_in[27];
  const float* c3_wr  = (const float*)d_in[28];
  const float* c3_br  = (const float*)d_in[29];
  const float* c3_we  = (const float*)d_in[30];
  const float* c3_att = (const float*)d_in[31];
  const float* c3_b   = (const float*)d_in[32];
  const float* pof_w  = (const float*)d_in[33];
  const float* pof_b  = (const float*)d_in[34];
  const float* hp_w   = (const float*)d_in[35];
  const float* hp_b   = (const float*)d_in[36];
  float* out = (float*)d_out;

  char* w = (char*)d_ws;
  double* scal  = (double*)(w + OFF_SCAL);
  float* gsum   = (float*)(w + OFF_GSUM);
  float* gcnt   = (float*)(w + OFF_GCNT);
  int* deg      = (int*)(w + OFF_DEG);
  int* rowptr   = (int*)(w + OFF_ROWPTR);
  int* cursor   = (int*)(w + OFF_CURSOR);
  int* bsum     = (int*)(w + OFF_BSUM);
  int* boff     = (int*)(w + OFF_BOFF);
  int2* col     = (int2*)(w + OFF_COL);
  float* alpha  = (float*)(w + OFF_ALPHA);
  float* A      = (float*)(w + OFF_A);
  float* B      = (float*)(w + OFF_B);
  float* C      = (float*)(w + OFF_C);
  float* h0     = C;   // [N,64] lives in C until layer-1 aggregate overwrites it

  hipMemsetAsync(d_ws, 0, ZERO_BYTES, stream);

  // CSR over dst (shared by all 3 layers)
  k_deg  <<<1024, 256, 0, stream>>>(ei, deg);
  k_scan1<<<196,  256, 0, stream>>>(deg, rowptr, bsum);
  k_scan2<<<1,    256, 0, stream>>>(bsum, boff, 196);
  k_scan3<<<196,  256, 0, stream>>>(rowptr, boff, cursor);
  k_fill <<<1024, 256, 0, stream>>>(ei, cursor, col);

  k_node_transform<<<12500, 256, 0, stream>>>(x, nt_w, nt_b, ln0_w, ln0_b, h0);

  // layer 1 (in 64, heads 2)
  k_lin<64,128><<<1024, 256, 0, stream>>>(h0, c1_wl, c1_bl, B, 256, 0);
  k_lin<64,128><<<1024, 256, 0, stream>>>(h0, c1_wr, c1_br, B, 256, 128);
  k_alpha<2><<<12500, 256, 0, stream>>>(B, c1_we, c1_att, ei, ea, alpha);
  k_agg<2>  <<<12500, 256, 0, stream>>>(B, alpha, rowptr, col, c1_b, C);
  k_gn_reduce<<<1024, 256, 0, stream>>>(C, scal);
  k_gn_apply <<<6250, 256, 0, stream>>>(C, scal, n1_w, n1_b, A);

  // layer 2 (in 128, heads 2)
  k_lin<128,128><<<1024, 256, 0, stream>>>(A, c2_wl, c2_bl, B, 256, 0);
  k_lin<128,128><<<1024, 256, 0, stream>>>(A, c2_wr, c2_br, B, 256, 128);
  k_alpha<2><<<12500, 256, 0, stream>>>(B, c2_we, c2_att, ei, ea, alpha);
  k_agg<2>  <<<12500, 256, 0, stream>>>(B, alpha, rowptr, col, c2_b, C);
  k_gn_reduce<<<1024, 256, 0, stream>>>(C, scal + 2);
  k_gn_apply <<<6250, 256, 0, stream>>>(C, scal + 2, n2_w, n2_b, A);

  // layer 3 (in 128, heads 1)
  k_lin<128,64><<<512, 256, 0, stream>>>(A, c3_wl, c3_bl, B, 128, 0);
  k_lin<128,64><<<512, 256, 0, stream>>>(A, c3_wr, c3_br, B, 128, 64);
  k_alpha<1><<<12500, 256, 0, stream>>>(B, c3_we, c3_att, ei, ea, alpha);
  k_agg<1>  <<<12500, 256, 0, stream>>>(B, alpha, rowptr, col, c3_b, C);

  // heads + pooling
  k_pool<<<512, 256, 0, stream>>>(C, batch, pof_w, pof_b, out, gsum, gcnt);
  k_head<<<1, 512, 0, stream>>>(gsum, gcnt, hp_w, hp_b, out);
}

// Round 2
// 1183.865 us; speedup vs baseline: 1.0421x; 1.0421x over previous
//
#include <hip/hip_runtime.h>
#include <cstdint>
#include <cstddef>

#define DI __device__ __forceinline__

constexpr int N = 50000;
constexpr int E = 800000;
constexpr int NG = 8;

// ---------- ws layout ----------
constexpr size_t AL(size_t x){ return (x + 1023) & ~size_t(1023); }
constexpr size_t OFF_SCAL   = 0;                          // 4 doubles (norm sums)
constexpr size_t OFF_GSUM   = 1024;                       // 512 floats
constexpr size_t OFF_GCNT   = OFF_GSUM + 2048;            // 8 floats
constexpr size_t OFF_DEG    = 4096;                       // N ints
constexpr size_t ZERO_BYTES = OFF_DEG + size_t(N)*4;      // zeroed each launch
constexpr size_t OFF_ROWPTR = AL(ZERO_BYTES);             // (N+1) ints
constexpr size_t OFF_CURSOR = AL(OFF_ROWPTR + size_t(N+1)*4);
constexpr size_t OFF_BSUM   = AL(OFF_CURSOR + size_t(N)*4);
constexpr size_t OFF_BOFF   = AL(OFF_BSUM + 1024);
constexpr size_t OFF_COL    = AL(OFF_BOFF + 1024);        // E int2
constexpr size_t OFF_A      = AL(OFF_COL + size_t(E)*8);     // N*128 f
constexpr size_t OFF_B      = AL(OFF_A + size_t(N)*128*4);   // N*256 f
constexpr size_t OFF_C      = AL(OFF_B + size_t(N)*256*4);   // N*128 f (also hosts h0 [N,64])

template<int START>
DI float wred(float v){
  #pragma unroll
  for (int o = START; o > 0; o >>= 1) v += __shfl_xor(v, o);
  return v;
}

DI float elu(float v){ return v > 0.f ? v : (__expf(v) - 1.f); }

// ---------- CSR build ----------
__global__ void k_deg(const int* __restrict__ ei, int* __restrict__ deg){
  for (int e = blockIdx.x*blockDim.x + threadIdx.x; e < E; e += gridDim.x*blockDim.x)
    atomicAdd(&deg[ei[E + e]], 1);
}

__global__ __launch_bounds__(256) void k_scan1(const int* __restrict__ deg,
                                               int* __restrict__ rowptr,
                                               int* __restrict__ bsum){
  __shared__ int s[256];
  int t = threadIdx.x, i = blockIdx.x*256 + t;
  int v = (i < N) ? deg[i] : 0;
  s[t] = v; __syncthreads();
  for (int off = 1; off < 256; off <<= 1){
    int x = (t >= off) ? s[t-off] : 0;
    __syncthreads();
    s[t] += x; __syncthreads();
  }
  if (i < N) rowptr[i] = s[t] - v;
  if (t == 255) bsum[blockIdx.x] = s[255];
}

__global__ __launch_bounds__(256) void k_scan2(const int* __restrict__ bsum,
                                               int* __restrict__ boff, int nb){
  __shared__ int s[256];
  int t = threadIdx.x;
  int v = (t < nb) ? bsum[t] : 0;
  s[t] = v; __syncthreads();
  for (int off = 1; off < 256; off <<= 1){
    int x = (t >= off) ? s[t-off] : 0;
    __syncthreads();
    s[t] += x; __syncthreads();
  }
  if (t < nb) boff[t] = s[t] - v;
}

__global__ __launch_bounds__(256) void k_scan3(int* __restrict__ rowptr,
                                               const int* __restrict__ boff,
                                               int* __restrict__ cursor){
  int t = threadIdx.x, i = blockIdx.x*256 + t;
  if (i < N){
    int v = rowptr[i] + boff[blockIdx.x];
    rowptr[i] = v;
    cursor[i] = v;
  }
  if (i == 0) rowptr[N] = E;
}

__global__ void k_fill(const int* __restrict__ ei, int* __restrict__ cursor,
                       int2* __restrict__ col){
  for (int e = blockIdx.x*blockDim.x + threadIdx.x; e < E; e += gridDim.x*blockDim.x){
    int d = ei[E + e];
    int pos = atomicAdd(&cursor[d], 1);
    col[pos] = make_int2(ei[e], e);
  }
}

// ---------- node transform: h0 = LN(elu(x @ nt_w + nt_b)) ----------
__global__ __launch_bounds__(256) void k_node_transform(
    const float* __restrict__ x, const float* __restrict__ w,
    const float* __restrict__ b, const float* __restrict__ lnw,
    const float* __restrict__ lnb, float* __restrict__ h0){
  int wid = (blockIdx.x*256 + threadIdx.x) >> 6;
  int l = threadIdx.x & 63;
  if (wid >= N) return;
  float xv = x[wid*32 + (l & 31)];
  float acc = b[l];
  #pragma unroll
  for (int k = 0; k < 32; ++k){
    float hk = __shfl(xv, k);
    acc = fmaf(hk, w[k*64 + l], acc);
  }
  float v = elu(acc);
  float mu = wred<32>(v) * (1.f/64.f);
  float xc = v - mu;
  float var = wred<32>(xc*xc) * (1.f/64.f);
  float rs = rsqrtf(var + 1e-5f);
  h0[wid*64 + l] = xc*rs*lnw[l] + lnb[l];
}

// ---------- combined linear: out[:,0:C] = h@Wl+bl ; out[:,C:2C] = h@Wr+br ----------
template<int K, int CTOT>
__global__ __launch_bounds__(256) void k_lin2(
    const float* __restrict__ h,
    const float* __restrict__ Wl_, const float* __restrict__ bl_,
    const float* __restrict__ Wr_, const float* __restrict__ br_,
    float* __restrict__ out){
  constexpr int C = CTOT/2;
  constexpr int CB = 64;
  constexpr int NCB = CTOT / CB;
  constexpr int NT = 32;
  constexpr int KQ = K / 4;
  __shared__ float Wl[K][CB];
  __shared__ float Hl[NT][K + 4];
  const int tid = threadIdx.x;
  const int cb = blockIdx.x % NCB;
  const int tile0 = blockIdx.x / NCB;
  const int tstep = gridDim.x / NCB;
  const bool left = cb < C/CB;
  const float* W = left ? Wl_ : Wr_;
  const float* bias = left ? bl_ : br_;
  const int wcb = left ? cb : cb - C/CB;
  for (int idx = tid; idx < K*CB; idx += 256){
    int k = idx >> 6, c = idx & 63;
    Wl[k][c] = W[k*C + wcb*CB + c];
  }
  const int nl = tid >> 4;
  const int cq = tid & 15;
  const float* bb = bias + wcb*CB + cq*4;
  float4 b4 = make_float4(bb[0], bb[1], bb[2], bb[3]);
  constexpr int NTILES = (N + NT - 1)/NT;
  for (int tile = tile0; tile < NTILES; tile += tstep){
    int n0 = tile*NT;
    __syncthreads();
    for (int idx = tid; idx < NT*KQ; idx += 256){
      int nn = idx / KQ, kq = idx % KQ;
      float4 v = make_float4(0,0,0,0);
      int n = n0 + nn;
      if (n < N) v = ((const float4*)(h + size_t(n)*K))[kq];
      *(((float4*)&Hl[nn][0]) + kq) = v;
    }
    __syncthreads();
    float4 a0 = make_float4(0,0,0,0), a1 = a0;
    #pragma unroll 8
    for (int k = 0; k < K; ++k){
      float4 w4 = ((const float4*)&Wl[k][0])[cq];
      float h0v = Hl[nl][k];
      float h1v = Hl[nl+16][k];
      a0.x = fmaf(h0v, w4.x, a0.x); a0.y = fmaf(h0v, w4.y, a0.y);
      a0.z = fmaf(h0v, w4.z, a0.z); a0.w = fmaf(h0v, w4.w, a0.w);
      a1.x = fmaf(h1v, w4.x, a1.x); a1.y = fmaf(h1v, w4.y, a1.y);
      a1.z = fmaf(h1v, w4.z, a1.z); a1.w = fmaf(h1v, w4.w, a1.w);
    }
    int na = n0 + nl, nb2 = n0 + nl + 16;
    if (na < N){
      float4 o = make_float4(a0.x+b4.x, a0.y+b4.y, a0.z+b4.z, a0.w+b4.w);
      ((float4*)(out + size_t(na)*CTOT + cb*CB))[cq] = o;
    }
    if (nb2 < N){
      float4 o = make_float4(a1.x+b4.x, a1.y+b4.y, a1.z+b4.z, a1.w+b4.w);
      ((float4*)(out + size_t(nb2)*CTOT + cb*CB))[cq] = o;
    }
  }
}

// ---------- fused attention + aggregate (per-node CSR, online softmax) ----------
// One wave per node. we/att register-resident. Optionally accumulates graph-norm
// sums (sum, sum^2) of the output into scal[0..1].
template<int H, bool GN>
__global__ __launch_bounds__(256) void k_attagg(
    const float* __restrict__ xlr, const float* __restrict__ we,
    const float* __restrict__ att, const float* __restrict__ ea,
    const int* __restrict__ rowptr, const int2* __restrict__ col,
    const float* __restrict__ bias, float* __restrict__ out,
    double* __restrict__ scal){
  constexpr int HC = H*64;
  constexpr int STRIDE = 2*HC;
  const int tid = threadIdx.x;
  const int l = tid & 63;
  const int n = (blockIdx.x*256 + tid) >> 6;
  float s1p = 0.f, s2p = 0.f;
  if (n < N){
    const int beg = rowptr[n], end = rowptr[n+1];
    if constexpr (H == 2){
      float2 wr_[16];
      const float2* we2 = (const float2*)we;
      #pragma unroll
      for (int k = 0; k < 16; ++k) wr_[k] = we2[k*64 + l];
      const float2 at = ((const float2*)att)[l];
      const float2 xr = ((const float2*)(xlr + size_t(n)*STRIDE + HC))[l];
      float m = -INFINITY, d = 0.f, acc0 = 0.f, acc1 = 0.f;
      int2 ent = (beg < end) ? col[beg] : make_int2(0,0);
      for (int i = beg; i < end; ++i){
        int2 nent = (i+1 < end) ? col[i+1] : ent;
        const float4* eap = (const float4*)(ea + size_t(ent.y)*16);
        float4 e0 = eap[0], e1 = eap[1], e2 = eap[2], e3 = eap[3];
        float2 xl = ((const float2*)(xlr + size_t(ent.x)*STRIDE))[l];
        float ev[16] = {e0.x,e0.y,e0.z,e0.w, e1.x,e1.y,e1.z,e1.w,
                        e2.x,e2.y,e2.z,e2.w, e3.x,e3.y,e3.z,e3.w};
        float c0 = xl.x + xr.x, c1 = xl.y + xr.y;
        #pragma unroll
        for (int k = 0; k < 16; ++k){
          c0 = fmaf(ev[k], wr_[k].x, c0);
          c1 = fmaf(ev[k], wr_[k].y, c1);
        }
        c0 = c0 > 0.f ? c0 : 0.2f*c0;
        c1 = c1 > 0.f ? c1 : 0.2f*c1;
        float a = wred<16>(c0*at.x + c1*at.y);   // per-head reduce in 32-lane half
        if (a > m){
          float sc = __expf(m - a);              // exp(-inf)=0 on first edge
          d *= sc; acc0 *= sc; acc1 *= sc; m = a;
        }
        float p = __expf(a - m);
        d += p;
        acc0 = fmaf(p, xl.x, acc0);
        acc1 = fmaf(p, xl.y, acc1);
        ent = nent;
      }
      float inv = 1.f/(d + 1e-16f);
      float o0 = acc0*inv + bias[2*l];
      float o1 = acc1*inv + bias[2*l+1];
      ((float2*)(out + size_t(n)*HC))[l] = make_float2(o0, o1);
      if constexpr (GN){ s1p = o0 + o1; s2p = o0*o0 + o1*o1; }
    } else {
      float wr_[16];
      #pragma unroll
      for (int k = 0; k < 16; ++k) wr_[k] = we[k*64 + l];
      const float at = att[l];
      const float xr = xlr[size_t(n)*STRIDE + HC + l];
      float m = -INFINITY, d = 0.f, acc0 = 0.f;
      int2 ent = (beg < end) ? col[beg] : make_int2(0,0);
      for (int i = beg; i < end; ++i){
        int2 nent = (i+1 < end) ? col[i+1] : ent;
        const float4* eap = (const float4*)(ea + size_t(ent.y)*16);
        float4 e0 = eap[0], e1 = eap[1], e2 = eap[2], e3 = eap[3];
        float xl = xlr[size_t(ent.x)*STRIDE + l];
        float ev[16] = {e0.x,e0.y,e0.z,e0.w, e1.x,e1.y,e1.z,e1.w,
                        e2.x,e2.y,e2.z,e2.w, e3.x,e3.y,e3.z,e3.w};
        float c0 = xl + xr;
        #pragma unroll
        for (int k = 0; k < 16; ++k) c0 = fmaf(ev[k], wr_[k], c0);
        c0 = c0 > 0.f ? c0 : 0.2f*c0;
        float a = wred<32>(c0*at);
        if (a > m){
          float sc = __expf(m - a);
          d *= sc; acc0 *= sc; m = a;
        }
        float p = __expf(a - m);
        d += p;
        acc0 = fmaf(p, xl, acc0);
        ent = nent;
      }
      out[size_t(n)*HC + l] = acc0/(d + 1e-16f) + bias[l];
      // GN never used for H==1
    }
  }
  if constexpr (GN){
    float s = wred<32>(s1p), s2 = wred<32>(s2p);
    __shared__ float bs[4], bs2[4];
    int w = tid >> 6;
    if ((tid & 63) == 0){ bs[w] = s; bs2[w] = s2; }
    __syncthreads();
    if (tid == 0){
      double ts  = (double)bs[0] + (double)bs[1] + (double)bs[2] + (double)bs[3];
      double ts2 = (double)bs2[0] + (double)bs2[1] + (double)bs2[2] + (double)bs2[3];
      atomicAdd(&scal[0], ts);
      atomicAdd(&scal[1], ts2);
    }
  }
}

// ---------- graph norm apply + ELU ----------
__global__ __launch_bounds__(256) void k_gn_apply(
    const float* __restrict__ xin, const double* __restrict__ scal,
    const float* __restrict__ w, const float* __restrict__ b,
    float* __restrict__ out){
  const double invM = 1.0 / (double(N)*128.0);
  double mu_d = scal[0]*invM;
  double ex2  = scal[1]*invM;
  float mu = (float)mu_d;
  float var = (float)(ex2 - mu_d*mu_d);
  float rs = rsqrtf(var + 1e-5f);
  const size_t M4 = size_t(N)*128/4;
  for (size_t i = size_t(blockIdx.x)*256 + threadIdx.x; i < M4; i += size_t(gridDim.x)*256){
    float4 v = ((const float4*)xin)[i];
    int cq = int(i & 31);
    float4 wv = ((const float4*)w)[cq];
    float4 bv = ((const float4*)b)[cq];
    v.x = elu((v.x - mu)*rs*wv.x + bv.x);
    v.y = elu((v.y - mu)*rs*wv.y + bv.y);
    v.z = elu((v.z - mu)*rs*wv.z + bv.z);
    v.w = elu((v.w - mu)*rs*wv.w + bv.w);
    ((float4*)out)[i] = v;
  }
}

// ---------- heads + pooling ----------
__global__ __launch_bounds__(256) void k_pool(
    const float* __restrict__ h3, const int* __restrict__ batch,
    const float* __restrict__ pw, const float* __restrict__ pb,
    float* __restrict__ outv, float* __restrict__ gsum, float* __restrict__ gcnt){
  __shared__ float ls[512];
  __shared__ float lc[8];
  int tid = threadIdx.x;
  if (tid < 8) lc[tid] = 0.f;
  for (int i = tid; i < 512; i += 256) ls[i] = 0.f;
  __syncthreads();
  int l = tid & 63;
  int wid = (blockIdx.x*256 + tid) >> 6;
  int NW = (gridDim.x*256) >> 6;
  float pwl = pw[l];
  for (int n = wid; n < N; n += NW){
    float v = h3[size_t(n)*64 + l];
    float pp = wred<32>(v*pwl);
    if (l == 0) outv[n] = pp + pb[0];
    int g = batch[n];
    atomicAdd(&ls[g*64 + l], v);
    if (l == 0) atomicAdd(&lc[g], 1.f);
  }
  __syncthreads();
  for (int i = tid; i < 512; i += 256) atomicAdd(&gsum[i], ls[i]);
  if (tid < 8) atomicAdd(&gcnt[tid], lc[tid]);
}

__global__ __launch_bounds__(512) void k_head(
    const float* __restrict__ gsum, const float* __restrict__ gcnt,
    const float* __restrict__ hw, const float* __restrict__ hb,
    float* __restrict__ outv){
  int g = threadIdx.x >> 6, l = threadIdx.x & 63;
  float cnt = fmaxf(gcnt[g], 1.f);
  float emb = gsum[g*64 + l] / cnt;
  float p = wred<32>(emb*hw[l]);
  if (l == 0) outv[N + g] = p + hb[0];
}

extern "C" void kernel_launch(void* const* d_in, const int* in_sizes, int n_in,
                              void* d_out, int out_size, void* d_ws, size_t ws_size,
                              hipStream_t stream){
  const float* x      = (const float*)d_in[0];
  const int*   ei     = (const int*)  d_in[1];
  const float* ea     = (const float*)d_in[2];
  const int*   batch  = (const int*)  d_in[3];
  const float* nt_w   = (const float*)d_in[4];
  const float* nt_b   = (const float*)d_in[5];
  const float* ln0_w  = (const float*)d_in[6];
  const float* ln0_b  = (const float*)d_in[7];
  const float* c1_wl  = (const float*)d_in[8];
  const float* c1_bl  = (const float*)d_in[9];
  const float* c1_wr  = (const float*)d_in[10];
  const float* c1_br  = (const float*)d_in[11];
  const float* c1_we  = (const float*)d_in[12];
  const float* c1_att = (const float*)d_in[13];
  const float* c1_b   = (const float*)d_in[14];
  const float* n1_w   = (const float*)d_in[15];
  const float* n1_b   = (const float*)d_in[16];
  const float* c2_wl  = (const float*)d_in[17];
  const float* c2_bl  = (const float*)d_in[18];
  const float* c2_wr  = (const float*)d_in[19];
  const float* c2_br  = (const float*)d_in[20];
  const float* c2_we  = (const float*)d_in[21];
  const float* c2_att = (const float*)d_in[22];
  const float* c2_b   = (const float*)d_in[23];
  const float* n2_w   = (const float*)d_in[24];
  const float* n2_b   = (const float*)d_in[25];
  const float* c3_wl  = (const float*)d_in[26];
  const float* c3_bl  = (const float*)d_in[27];
  const float* c3_wr  = (const float*)d_in[28];
  const float* c3_br  = (const float*)d_in[29];
  const float* c3_we  = (const float*)d_in[30];
  const float* c3_att = (const float*)d_in[31];
  const float* c3_b   = (const float*)d_in[32];
  const float* pof_w  = (const float*)d_in[33];
  const float* pof_b  = (const float*)d_in[34];
  const float* hp_w   = (const float*)d_in[35];
  const float* hp_b   = (const float*)d_in[36];
  float* out = (float*)d_out;

  char* w = (char*)d_ws;
  double* scal  = (double*)(w + OFF_SCAL);
  float* gsum   = (float*)(w + OFF_GSUM);
  float* gcnt   = (float*)(w + OFF_GCNT);
  int* deg      = (int*)(w + OFF_DEG);
  int* rowptr   = (int*)(w + OFF_ROWPTR);
  int* cursor   = (int*)(w + OFF_CURSOR);
  int* bsum     = (int*)(w + OFF_BSUM);
  int* boff     = (int*)(w + OFF_BOFF);
  int2* col     = (int2*)(w + OFF_COL);
  float* A      = (float*)(w + OFF_A);
  float* B      = (float*)(w + OFF_B);
  float* C      = (float*)(w + OFF_C);
  float* h0     = C;   // [N,64] lives in C until layer-1 aggregate overwrites it

  hipMemsetAsync(d_ws, 0, ZERO_BYTES, stream);

  // CSR over dst (shared by all 3 layers)
  k_deg  <<<1024, 256, 0, stream>>>(ei, deg);
  k_scan1<<<196,  256, 0, stream>>>(deg, rowptr, bsum);
  k_scan2<<<1,    256, 0, stream>>>(bsum, boff, 196);
  k_scan3<<<196,  256, 0, stream>>>(rowptr, boff, cursor);
  k_fill <<<1024, 256, 0, stream>>>(ei, cursor, col);

  k_node_transform<<<12500, 256, 0, stream>>>(x, nt_w, nt_b, ln0_w, ln0_b, h0);

  // layer 1 (in 64, heads 2)
  k_lin2<64,256><<<2048, 256, 0, stream>>>(h0, c1_wl, c1_bl, c1_wr, c1_br, B);
  k_attagg<2,true><<<12500, 256, 0, stream>>>(B, c1_we, c1_att, ea, rowptr, col, c1_b, C, scal);
  k_gn_apply<<<6250, 256, 0, stream>>>(C, scal, n1_w, n1_b, A);

  // layer 2 (in 128, heads 2)
  k_lin2<128,256><<<2048, 256, 0, stream>>>(A, c2_wl, c2_bl, c2_wr, c2_br, B);
  k_attagg<2,true><<<12500, 256, 0, stream>>>(B, c2_we, c2_att, ea, rowptr, col, c2_b, C, scal + 2);
  k_gn_apply<<<6250, 256, 0, stream>>>(C, scal + 2, n2_w, n2_b, A);

  // layer 3 (in 128, heads 1)
  k_lin2<128,128><<<1024, 256, 0, stream>>>(A, c3_wl, c3_bl, c3_wr, c3_br, B);
  k_attagg<1,false><<<12500, 256, 0, stream>>>(B, c3_we, c3_att, ea, rowptr, col, c3_b, C, nullptr);

  // heads + pooling
  k_pool<<<512, 256, 0, stream>>>(C, batch, pof_w, pof_b, out, gsum, gcnt);
  k_head<<<1, 512, 0, stream>>>(gsum, gcnt, hp_w, hp_b, out);
}

// Round 3
// 1008.636 us; speedup vs baseline: 1.2231x; 1.1737x over previous
//
#include <hip/hip_runtime.h>
#include <cstdint>
#include <cstddef>

#define DI __device__ __forceinline__

constexpr int N = 50000;
constexpr int E = 800000;
constexpr int NG = 8;

// ---------- ws layout ----------
constexpr size_t AL(size_t x){ return (x + 1023) & ~size_t(1023); }
constexpr size_t OFF_SCAL   = 0;                          // 4 doubles (norm sums)
constexpr size_t OFF_GSUM   = 1024;                       // 512 floats
constexpr size_t OFF_GCNT   = OFF_GSUM + 2048;            // 8 floats
constexpr size_t OFF_DEG    = 4096;                       // N ints
constexpr size_t ZERO_BYTES = OFF_DEG + size_t(N)*4;      // zeroed each launch
constexpr size_t OFF_ROWPTR = AL(ZERO_BYTES);             // (N+1) ints
constexpr size_t OFF_CURSOR = AL(OFF_ROWPTR + size_t(N+1)*4);
constexpr size_t OFF_BSUM   = AL(OFF_CURSOR + size_t(N)*4);
constexpr size_t OFF_BOFF   = AL(OFF_BSUM + 1024);
constexpr size_t OFF_COLSRC = AL(OFF_BOFF + 1024);        // E ints
constexpr size_t OFF_EAC    = AL(OFF_COLSRC + size_t(E)*4);   // E * 8 u32 (16 bf16)
constexpr size_t OFF_B      = AL(OFF_EAC + size_t(E)*32);     // N*256 f
constexpr size_t OFF_C      = AL(OFF_B + size_t(N)*256*4);    // N*128 f (also h0 [N,64])
// total ~106 MB

template<int START>
DI float wred(float v){
  #pragma unroll
  for (int o = START; o > 0; o >>= 1) v += __shfl_xor(v, o);
  return v;
}

DI float elu(float v){ return v > 0.f ? v : (__expf(v) - 1.f); }

// bf16 pack (RTN) / unpack
DI uint32_t bfr(float x){ uint32_t u = __float_as_uint(x); return (u + 0x7fffu + ((u >> 16) & 1u)) >> 16; }
DI uint32_t pk2(float a, float b){ return bfr(a) | (bfr(b) << 16); }
DI float lo16(uint32_t u){ return __uint_as_float(u << 16); }
DI float hi16(uint32_t u){ return __uint_as_float(u & 0xffff0000u); }

// ---------- CSR build ----------
__global__ void k_deg(const int* __restrict__ ei, int* __restrict__ deg){
  for (int e = blockIdx.x*blockDim.x + threadIdx.x; e < E; e += gridDim.x*blockDim.x)
    atomicAdd(&deg[ei[E + e]], 1);
}

__global__ __launch_bounds__(256) void k_scan1(const int* __restrict__ deg,
                                               int* __restrict__ rowptr,
                                               int* __restrict__ bsum){
  __shared__ int s[256];
  int t = threadIdx.x, i = blockIdx.x*256 + t;
  int v = (i < N) ? deg[i] : 0;
  s[t] = v; __syncthreads();
  for (int off = 1; off < 256; off <<= 1){
    int x = (t >= off) ? s[t-off] : 0;
    __syncthreads();
    s[t] += x; __syncthreads();
  }
  if (i < N) rowptr[i] = s[t] - v;
  if (t == 255) bsum[blockIdx.x] = s[255];
}

__global__ __launch_bounds__(256) void k_scan2(const int* __restrict__ bsum,
                                               int* __restrict__ boff, int nb){
  __shared__ int s[256];
  int t = threadIdx.x;
  int v = (t < nb) ? bsum[t] : 0;
  s[t] = v; __syncthreads();
  for (int off = 1; off < 256; off <<= 1){
    int x = (t >= off) ? s[t-off] : 0;
    __syncthreads();
    s[t] += x; __syncthreads();
  }
  if (t < nb) boff[t] = s[t] - v;
}

__global__ __launch_bounds__(256) void k_scan3(int* __restrict__ rowptr,
                                               const int* __restrict__ boff,
                                               int* __restrict__ cursor){
  int t = threadIdx.x, i = blockIdx.x*256 + t;
  if (i < N){
    int v = rowptr[i] + boff[blockIdx.x];
    rowptr[i] = v;
    cursor[i] = v;
  }
  if (i == 0) rowptr[N] = E;
}

// fill: CSR col (src only) + edge_attr re-ordered into CSR order, bf16-packed
__global__ void k_fill(const int* __restrict__ ei, const float* __restrict__ ea,
                       int* __restrict__ cursor, int* __restrict__ colsrc,
                       uint32_t* __restrict__ eac){
  for (int e = blockIdx.x*blockDim.x + threadIdx.x; e < E; e += gridDim.x*blockDim.x){
    int dn = ei[E + e];
    int pos = atomicAdd(&cursor[dn], 1);
    colsrc[pos] = ei[e];
    const float4* s = (const float4*)(ea + size_t(e)*16);
    float4 v0 = s[0], v1 = s[1], v2 = s[2], v3 = s[3];
    uint32_t* d8 = eac + size_t(pos)*8;
    d8[0] = pk2(v0.x, v0.y); d8[1] = pk2(v0.z, v0.w);
    d8[2] = pk2(v1.x, v1.y); d8[3] = pk2(v1.z, v1.w);
    d8[4] = pk2(v2.x, v2.y); d8[5] = pk2(v2.z, v2.w);
    d8[6] = pk2(v3.x, v3.y); d8[7] = pk2(v3.z, v3.w);
  }
}

// ---------- node transform: h0 = LN(elu(x @ nt_w + nt_b)) ----------
__global__ __launch_bounds__(256) void k_node_transform(
    const float* __restrict__ x, const float* __restrict__ w,
    const float* __restrict__ b, const float* __restrict__ lnw,
    const float* __restrict__ lnb, float* __restrict__ h0){
  int wid = (blockIdx.x*256 + threadIdx.x) >> 6;
  int l = threadIdx.x & 63;
  if (wid >= N) return;
  float xv = x[wid*32 + (l & 31)];
  float acc = b[l];
  #pragma unroll
  for (int k = 0; k < 32; ++k){
    float hk = __shfl(xv, k);
    acc = fmaf(hk, w[k*64 + l], acc);
  }
  float v = elu(acc);
  float mu = wred<32>(v) * (1.f/64.f);
  float xc = v - mu;
  float var = wred<32>(xc*xc) * (1.f/64.f);
  float rs = rsqrtf(var + 1e-5f);
  h0[wid*64 + l] = xc*rs*lnw[l] + lnb[l];
}

// ---------- combined linear: out[:,0:C] = h@Wl+bl ; out[:,C:2C] = h@Wr+br ----------
template<int K, int CTOT>
__global__ __launch_bounds__(256) void k_lin2(
    const float* __restrict__ h,
    const float* __restrict__ Wl_, const float* __restrict__ bl_,
    const float* __restrict__ Wr_, const float* __restrict__ br_,
    float* __restrict__ out){
  constexpr int C = CTOT/2;
  constexpr int CB = 64;
  constexpr int NCB = CTOT / CB;
  constexpr int NT = 32;
  constexpr int KQ = K / 4;
  __shared__ float Wl[K][CB];
  __shared__ float Hl[NT][K + 4];
  const int tid = threadIdx.x;
  const int cb = blockIdx.x % NCB;
  const int tile0 = blockIdx.x / NCB;
  const int tstep = gridDim.x / NCB;
  const bool left = cb < C/CB;
  const float* W = left ? Wl_ : Wr_;
  const float* bias = left ? bl_ : br_;
  const int wcb = left ? cb : cb - C/CB;
  for (int idx = tid; idx < K*CB; idx += 256){
    int k = idx >> 6, c = idx & 63;
    Wl[k][c] = W[k*C + wcb*CB + c];
  }
  const int nl = tid >> 4;
  const int cq = tid & 15;
  const float* bb = bias + wcb*CB + cq*4;
  float4 b4 = make_float4(bb[0], bb[1], bb[2], bb[3]);
  constexpr int NTILES = (N + NT - 1)/NT;
  for (int tile = tile0; tile < NTILES; tile += tstep){
    int n0 = tile*NT;
    __syncthreads();
    for (int idx = tid; idx < NT*KQ; idx += 256){
      int nn = idx / KQ, kq = idx % KQ;
      float4 v = make_float4(0,0,0,0);
      int n = n0 + nn;
      if (n < N) v = ((const float4*)(h + size_t(n)*K))[kq];
      *(((float4*)&Hl[nn][0]) + kq) = v;
    }
    __syncthreads();
    float4 a0 = make_float4(0,0,0,0), a1 = a0;
    #pragma unroll 8
    for (int k = 0; k < K; ++k){
      float4 w4 = ((const float4*)&Wl[k][0])[cq];
      float h0v = Hl[nl][k];
      float h1v = Hl[nl+16][k];
      a0.x = fmaf(h0v, w4.x, a0.x); a0.y = fmaf(h0v, w4.y, a0.y);
      a0.z = fmaf(h0v, w4.z, a0.z); a0.w = fmaf(h0v, w4.w, a0.w);
      a1.x = fmaf(h1v, w4.x, a1.x); a1.y = fmaf(h1v, w4.y, a1.y);
      a1.z = fmaf(h1v, w4.z, a1.z); a1.w = fmaf(h1v, w4.w, a1.w);
    }
    int na = n0 + nl, nb2 = n0 + nl + 16;
    if (na < N){
      float4 o = make_float4(a0.x+b4.x, a0.y+b4.y, a0.z+b4.z, a0.w+b4.w);
      ((float4*)(out + size_t(na)*CTOT + cb*CB))[cq] = o;
    }
    if (nb2 < N){
      float4 o = make_float4(a1.x+b4.x, a1.y+b4.y, a1.z+b4.z, a1.w+b4.w);
      ((float4*)(out + size_t(nb2)*CTOT + cb*CB))[cq] = o;
    }
  }
}

// ---------- fused attention + aggregate (per-node CSR, max-free softmax) ----------
// One wave per node. 2-way edge unroll for MLP. ea pre-gathered in CSR order (bf16).
template<int H, bool GN>
__global__ __launch_bounds__(256) void k_attagg(
    const float* __restrict__ xlr, const float* __restrict__ we,
    const float* __restrict__ att, const uint32_t* __restrict__ eac,
    const int* __restrict__ rowptr, const int* __restrict__ colsrc,
    const float* __restrict__ bias, float* __restrict__ out,
    double* __restrict__ scal){
  constexpr int HC = H*64;
  constexpr int STRIDE = 2*HC;
  const int tid = threadIdx.x;
  const int l = tid & 63;
  const int n = (blockIdx.x*256 + tid) >> 6;
  float s1p = 0.f, s2p = 0.f;
  if (n < N){
    const int beg = __builtin_amdgcn_readfirstlane(rowptr[n]);
    const int end = __builtin_amdgcn_readfirstlane(rowptr[n+1]);
    const uint4* eb = (const uint4*)eac;
    if constexpr (H == 2){
      float2 wr_[16];
      const float2* we2 = (const float2*)we;
      #pragma unroll
      for (int k = 0; k < 16; ++k) wr_[k] = we2[k*64 + l];
      const float2 at2 = ((const float2*)att)[l];
      const float2 xr = ((const float2*)(xlr + size_t(n)*STRIDE + HC))[l];
      float d = 0.f, a0 = 0.f, a1 = 0.f;
      int i = beg;
      for (; i + 1 < end; i += 2){
        int s0 = colsrc[i], s1 = colsrc[i+1];
        uint4 q00 = eb[size_t(i)*2],   q01 = eb[size_t(i)*2+1];
        uint4 q10 = eb[size_t(i)*2+2], q11 = eb[size_t(i)*2+3];
        float2 xl0 = ((const float2*)(xlr + size_t(s0)*STRIDE))[l];
        float2 xl1 = ((const float2*)(xlr + size_t(s1)*STRIDE))[l];
        float c00 = xl0.x + xr.x, c01 = xl0.y + xr.y;
        float c10 = xl1.x + xr.x, c11 = xl1.y + xr.y;
        uint32_t w0[8] = {q00.x,q00.y,q00.z,q00.w, q01.x,q01.y,q01.z,q01.w};
        uint32_t w1[8] = {q10.x,q10.y,q10.z,q10.w, q11.x,q11.y,q11.z,q11.w};
        #pragma unroll
        for (int k = 0; k < 8; ++k){
          float e0 = lo16(w0[k]), e1 = hi16(w0[k]);
          float f0 = lo16(w1[k]), f1 = hi16(w1[k]);
          c00 = fmaf(e0, wr_[2*k].x, c00);   c01 = fmaf(e0, wr_[2*k].y, c01);
          c00 = fmaf(e1, wr_[2*k+1].x, c00); c01 = fmaf(e1, wr_[2*k+1].y, c01);
          c10 = fmaf(f0, wr_[2*k].x, c10);   c11 = fmaf(f0, wr_[2*k].y, c11);
          c10 = fmaf(f1, wr_[2*k+1].x, c10); c11 = fmaf(f1, wr_[2*k+1].y, c11);
        }
        c00 = c00 > 0.f ? c00 : 0.2f*c00;  c01 = c01 > 0.f ? c01 : 0.2f*c01;
        c10 = c10 > 0.f ? c10 : 0.2f*c10;  c11 = c11 > 0.f ? c11 : 0.2f*c11;
        float t0 = wred<16>(c00*at2.x + c01*at2.y);
        float t1 = wred<16>(c10*at2.x + c11*at2.y);
        float p0 = __expf(t0), p1 = __expf(t1);
        d += p0 + p1;
        a0 = fmaf(p0, xl0.x, a0); a1 = fmaf(p0, xl0.y, a1);
        a0 = fmaf(p1, xl1.x, a0); a1 = fmaf(p1, xl1.y, a1);
      }
      if (i < end){
        int s0 = colsrc[i];
        uint4 q00 = eb[size_t(i)*2], q01 = eb[size_t(i)*2+1];
        float2 xl0 = ((const float2*)(xlr + size_t(s0)*STRIDE))[l];
        float c00 = xl0.x + xr.x, c01 = xl0.y + xr.y;
        uint32_t w0[8] = {q00.x,q00.y,q00.z,q00.w, q01.x,q01.y,q01.z,q01.w};
        #pragma unroll
        for (int k = 0; k < 8; ++k){
          float e0 = lo16(w0[k]), e1 = hi16(w0[k]);
          c00 = fmaf(e0, wr_[2*k].x, c00);   c01 = fmaf(e0, wr_[2*k].y, c01);
          c00 = fmaf(e1, wr_[2*k+1].x, c00); c01 = fmaf(e1, wr_[2*k+1].y, c01);
        }
        c00 = c00 > 0.f ? c00 : 0.2f*c00;  c01 = c01 > 0.f ? c01 : 0.2f*c01;
        float t0 = wred<16>(c00*at2.x + c01*at2.y);
        float p0 = __expf(t0);
        d += p0;
        a0 = fmaf(p0, xl0.x, a0); a1 = fmaf(p0, xl0.y, a1);
      }
      float inv = 1.f/(d + 1e-16f);
      float o0 = a0*inv + bias[2*l];
      float o1 = a1*inv + bias[2*l+1];
      ((float2*)(out + size_t(n)*HC))[l] = make_float2(o0, o1);
      if constexpr (GN){ s1p = o0 + o1; s2p = o0*o0 + o1*o1; }
    } else {
      float wr_[16];
      #pragma unroll
      for (int k = 0; k < 16; ++k) wr_[k] = we[k*64 + l];
      const float at = att[l];
      const float xr = xlr[size_t(n)*STRIDE + HC + l];
      float d = 0.f, a0 = 0.f;
      int i = beg;
      for (; i + 1 < end; i += 2){
        int s0 = colsrc[i], s1 = colsrc[i+1];
        uint4 q00 = eb[size_t(i)*2],   q01 = eb[size_t(i)*2+1];
        uint4 q10 = eb[size_t(i)*2+2], q11 = eb[size_t(i)*2+3];
        float xl0 = xlr[size_t(s0)*STRIDE + l];
        float xl1 = xlr[size_t(s1)*STRIDE + l];
        float c0 = xl0 + xr, c1 = xl1 + xr;
        uint32_t w0[8] = {q00.x,q00.y,q00.z,q00.w, q01.x,q01.y,q01.z,q01.w};
        uint32_t w1[8] = {q10.x,q10.y,q10.z,q10.w, q11.x,q11.y,q11.z,q11.w};
        #pragma unroll
        for (int k = 0; k < 8; ++k){
          float e0 = lo16(w0[k]), e1 = hi16(w0[k]);
          float f0 = lo16(w1[k]), f1 = hi16(w1[k]);
          c0 = fmaf(e0, wr_[2*k], c0); c0 = fmaf(e1, wr_[2*k+1], c0);
          c1 = fmaf(f0, wr_[2*k], c1); c1 = fmaf(f1, wr_[2*k+1], c1);
        }
        c0 = c0 > 0.f ? c0 : 0.2f*c0;
        c1 = c1 > 0.f ? c1 : 0.2f*c1;
        float t0 = wred<32>(c0*at);
        float t1 = wred<32>(c1*at);
        float p0 = __expf(t0), p1 = __expf(t1);
        d += p0 + p1;
        a0 = fmaf(p0, xl0, a0);
        a0 = fmaf(p1, xl1, a0);
      }
      if (i < end){
        int s0 = colsrc[i];
        uint4 q00 = eb[size_t(i)*2], q01 = eb[size_t(i)*2+1];
        float xl0 = xlr[size_t(s0)*STRIDE + l];
        float c0 = xl0 + xr;
        uint32_t w0[8] = {q00.x,q00.y,q00.z,q00.w, q01.x,q01.y,q01.z,q01.w};
        #pragma unroll
        for (int k = 0; k < 8; ++k){
          float e0 = lo16(w0[k]), e1 = hi16(w0[k]);
          c0 = fmaf(e0, wr_[2*k], c0); c0 = fmaf(e1, wr_[2*k+1], c0);
        }
        c0 = c0 > 0.f ? c0 : 0.2f*c0;
        float t0 = wred<32>(c0*at);
        float p0 = __expf(t0);
        d += p0;
        a0 = fmaf(p0, xl0, a0);
      }
      out[size_t(n)*HC + l] = a0/(d + 1e-16f) + bias[l];
    }
  }
  if constexpr (GN){
    float s = wred<32>(s1p), s2 = wred<32>(s2p);
    __shared__ float bs[4], bs2[4];
    int w = tid >> 6;
    if ((tid & 63) == 0){ bs[w] = s; bs2[w] = s2; }
    __syncthreads();
    if (tid == 0){
      double ts  = (double)bs[0] + (double)bs[1] + (double)bs[2] + (double)bs[3];
      double ts2 = (double)bs2[0] + (double)bs2[1] + (double)bs2[2] + (double)bs2[3];
      atomicAdd(&scal[0], ts);
      atomicAdd(&scal[1], ts2);
    }
  }
}

// ---------- graph norm apply + ELU (in-place safe: elementwise) ----------
__global__ __launch_bounds__(256) void k_gn_apply(
    const float* __restrict__ xin, const double* __restrict__ scal,
    const float* __restrict__ w, const float* __restrict__ b,
    float* __restrict__ out){
  const double invM = 1.0 / (double(N)*128.0);
  double mu_d = scal[0]*invM;
  double ex2  = scal[1]*invM;
  float mu = (float)mu_d;
  float var = (float)(ex2 - mu_d*mu_d);
  float rs = rsqrtf(var + 1e-5f);
  const size_t M4 = size_t(N)*128/4;
  for (size_t i = size_t(blockIdx.x)*256 + threadIdx.x; i < M4; i += size_t(gridDim.x)*256){
    float4 v = ((const float4*)xin)[i];
    int cq = int(i & 31);
    float4 wv = ((const float4*)w)[cq];
    float4 bv = ((const float4*)b)[cq];
    v.x = elu((v.x - mu)*rs*wv.x + bv.x);
    v.y = elu((v.y - mu)*rs*wv.y + bv.y);
    v.z = elu((v.z - mu)*rs*wv.z + bv.z);
    v.w = elu((v.w - mu)*rs*wv.w + bv.w);
    ((float4*)out)[i] = v;
  }
}

// ---------- heads + pooling ----------
__global__ __launch_bounds__(256) void k_pool(
    const float* __restrict__ h3, const int* __restrict__ batch,
    const float* __restrict__ pw, const float* __restrict__ pb,
    float* __restrict__ outv, float* __restrict__ gsum, float* __restrict__ gcnt){
  __shared__ float ls[512];
  __shared__ float lc[8];
  int tid = threadIdx.x;
  if (tid < 8) lc[tid] = 0.f;
  for (int i = tid; i < 512; i += 256) ls[i] = 0.f;
  __syncthreads();
  int l = tid & 63;
  int wid = (blockIdx.x*256 + tid) >> 6;
  int NW = (gridDim.x*256) >> 6;
  float pwl = pw[l];
  for (int n = wid; n < N; n += NW){
    float v = h3[size_t(n)*64 + l];
    float pp = wred<32>(v*pwl);
    if (l == 0) outv[n] = pp + pb[0];
    int g = batch[n];
    atomicAdd(&ls[g*64 + l], v);
    if (l == 0) atomicAdd(&lc[g], 1.f);
  }
  __syncthreads();
  for (int i = tid; i < 512; i += 256) atomicAdd(&gsum[i], ls[i]);
  if (tid < 8) atomicAdd(&gcnt[tid], lc[tid]);
}

__global__ __launch_bounds__(512) void k_head(
    const float* __restrict__ gsum, const float* __restrict__ gcnt,
    const float* __restrict__ hw, const float* __restrict__ hb,
    float* __restrict__ outv){
  int g = threadIdx.x >> 6, l = threadIdx.x & 63;
  float cnt = fmaxf(gcnt[g], 1.f);
  float emb = gsum[g*64 + l] / cnt;
  float p = wred<32>(emb*hw[l]);
  if (l == 0) outv[N + g] = p + hb[0];
}

extern "C" void kernel_launch(void* const* d_in, const int* in_sizes, int n_in,
                              void* d_out, int out_size, void* d_ws, size_t ws_size,
                              hipStream_t stream){
  const float* x      = (const float*)d_in[0];
  const int*   ei     = (const int*)  d_in[1];
  const float* ea     = (const float*)d_in[2];
  const int*   batch  = (const int*)  d_in[3];
  const float* nt_w   = (const float*)d_in[4];
  const float* nt_b   = (const float*)d_in[5];
  const float* ln0_w  = (const float*)d_in[6];
  const float* ln0_b  = (const float*)d_in[7];
  const float* c1_wl  = (const float*)d_in[8];
  const float* c1_bl  = (const float*)d_in[9];
  const float* c1_wr  = (const float*)d_in[10];
  const float* c1_br  = (const float*)d_in[11];
  const float* c1_we  = (const float*)d_in[12];
  const float* c1_att = (const float*)d_in[13];
  const float* c1_b   = (const float*)d_in[14];
  const float* n1_w   = (const float*)d_in[15];
  const float* n1_b   = (const float*)d_in[16];
  const float* c2_wl  = (const float*)d_in[17];
  const float* c2_bl  = (const float*)d_in[18];
  const float* c2_wr  = (const float*)d_in[19];
  const float* c2_br  = (const float*)d_in[20];
  const float* c2_we  = (const float*)d_in[21];
  const float* c2_att = (const float*)d_in[22];
  const float* c2_b   = (const float*)d_in[23];
  const float* n2_w   = (const float*)d_in[24];
  const float* n2_b   = (const float*)d_in[25];
  const float* c3_wl  = (const float*)d_in[26];
  const float* c3_bl  = (const float*)d_in[27];
  const float* c3_wr  = (const float*)d_in[28];
  const float* c3_br  = (const float*)d_in[29];
  const float* c3_we  = (const float*)d_in[30];
  const float* c3_att = (const float*)d_in[31];
  const float* c3_b   = (const float*)d_in[32];
  const float* pof_w  = (const float*)d_in[33];
  const float* pof_b  = (const float*)d_in[34];
  const float* hp_w   = (const float*)d_in[35];
  const float* hp_b   = (const float*)d_in[36];
  float* out = (float*)d_out;

  char* w = (char*)d_ws;
  double* scal    = (double*)(w + OFF_SCAL);
  float* gsum     = (float*)(w + OFF_GSUM);
  float* gcnt     = (float*)(w + OFF_GCNT);
  int* deg        = (int*)(w + OFF_DEG);
  int* rowptr     = (int*)(w + OFF_ROWPTR);
  int* cursor     = (int*)(w + OFF_CURSOR);
  int* bsum       = (int*)(w + OFF_BSUM);
  int* boff       = (int*)(w + OFF_BOFF);
  int* colsrc     = (int*)(w + OFF_COLSRC);
  uint32_t* eac   = (uint32_t*)(w + OFF_EAC);
  float* B        = (float*)(w + OFF_B);
  float* C        = (float*)(w + OFF_C);
  float* h0       = C;   // [N,64] lives in C until layer-1 aggregate overwrites it

  hipMemsetAsync(d_ws, 0, ZERO_BYTES, stream);

  // CSR over dst (shared by all 3 layers) + ea re-order (bf16)
  k_deg  <<<1024, 256, 0, stream>>>(ei, deg);
  k_scan1<<<196,  256, 0, stream>>>(deg, rowptr, bsum);
  k_scan2<<<1,    256, 0, stream>>>(bsum, boff, 196);
  k_scan3<<<196,  256, 0, stream>>>(rowptr, boff, cursor);
  k_fill <<<1024, 256, 0, stream>>>(ei, ea, cursor, colsrc, eac);

  k_node_transform<<<12500, 256, 0, stream>>>(x, nt_w, nt_b, ln0_w, ln0_b, h0);

  // layer 1 (in 64, heads 2)
  k_lin2<64,256><<<2048, 256, 0, stream>>>(h0, c1_wl, c1_bl, c1_wr, c1_br, B);
  k_attagg<2,true><<<12500, 256, 0, stream>>>(B, c1_we, c1_att, eac, rowptr, colsrc, c1_b, C, scal);
  k_gn_apply<<<6250, 256, 0, stream>>>(C, scal, n1_w, n1_b, C);

  // layer 2 (in 128, heads 2)
  k_lin2<128,256><<<2048, 256, 0, stream>>>(C, c2_wl, c2_bl, c2_wr, c2_br, B);
  k_attagg<2,true><<<12500, 256, 0, stream>>>(B, c2_we, c2_att, eac, rowptr, colsrc, c2_b, C, scal + 2);
  k_gn_apply<<<6250, 256, 0, stream>>>(C, scal + 2, n2_w, n2_b, C);

  // layer 3 (in 128, heads 1)
  k_lin2<128,128><<<1024, 256, 0, stream>>>(C, c3_wl, c3_bl, c3_wr, c3_br, B);
  k_attagg<1,false><<<12500, 256, 0, stream>>>(B, c3_we, c3_att, eac, rowptr, colsrc, c3_b, C, nullptr);

  // heads + pooling
  k_pool<<<512, 256, 0, stream>>>(C, batch, pof_w, pof_b, out, gsum, gcnt);
  k_head<<<1, 512, 0, stream>>>(gsum, gcnt, hp_w, hp_b, out);
}